// Round 1
// baseline (253.592 us; speedup 1.0000x reference)
//
#include <hip/hip_runtime.h>

// out[n,i,j] = sum_k x[n,i,k] * w[i,j,k] + b[i,j]
// N=128, D=512. One workgroup per i: C_i = X_i (128x512) @ W_i^T (512x512) + b[i,:]
// Memory-bound: ~805 MB total HBM traffic -> ~128us floor at 6.3 TB/s.

#define Nn 128
#define Dd 512
#define BK 64

typedef __attribute__((ext_vector_type(8))) short bf16x8;   // MFMA A/B fragment (4 VGPR)
typedef __attribute__((ext_vector_type(4))) short bf16x4;   // 8B LDS write
typedef __attribute__((ext_vector_type(4))) float f32x4;    // MFMA C/D fragment

__device__ __forceinline__ unsigned short f2bf(float f) {
    unsigned u = __builtin_bit_cast(unsigned, f);
    u += 0x7FFFu + ((u >> 16) & 1u);      // round-to-nearest-even
    return (unsigned short)(u >> 16);
}

__global__ __launch_bounds__(512, 2)
void linear3d_kernel(const float* __restrict__ x,
                     const float* __restrict__ w,
                     const float* __restrict__ b,
                     float* __restrict__ out) {
    const int i    = blockIdx.x;
    const int tid  = threadIdx.x;
    const int lane = tid & 63;
    const int wid  = tid >> 6;            // 8 waves; wave wid owns j-slice [wid*64, wid*64+64)

    // bf16 tiles, row stride = BK*2 = 128 bytes, XOR-swizzled by ((row&7)<<4)
    __shared__ short lds_x[Nn * BK];      // [n][k]  16 KB
    __shared__ short lds_w[Dd * BK];      // [j][k]  64 KB

    const float* xi = x + (size_t)i * Dd;            // x[n,i,k] = xi[n*Dd*Dd + k]
    const float* wi = w + (size_t)i * Dd * Dd;       // w[i,j,k] = wi[j*Dd + k]

    f32x4 acc[8][4];
    #pragma unroll
    for (int m = 0; m < 8; ++m)
        #pragma unroll
        for (int n = 0; n < 4; ++n)
            acc[m][n] = (f32x4){0.f, 0.f, 0.f, 0.f};

    // bias depends only on j; load the 4 values this lane's output columns need
    float bias_v[4];
    #pragma unroll
    for (int nt = 0; nt < 4; ++nt)
        bias_v[nt] = b[i * Dd + wid * 64 + nt * 16 + (lane & 15)];

    for (int k0 = 0; k0 < Dd; k0 += BK) {
        __syncthreads();   // protect previous iteration's LDS reads

        // ---- stage X chunk: 128 rows x 64 k, f32 -> bf16, 2048 float4 = 4/thread
        #pragma unroll
        for (int p = 0; p < 4; ++p) {
            int idx4 = tid + p * 512;
            int row  = idx4 >> 4;          // n (16 float4 per row)
            int c4   = idx4 & 15;
            float4 v = *(const float4*)(xi + (size_t)row * (Dd * Dd) + k0 + c4 * 4);
            bf16x4 h;
            h[0] = (short)f2bf(v.x); h[1] = (short)f2bf(v.y);
            h[2] = (short)f2bf(v.z); h[3] = (short)f2bf(v.w);
            int byte = row * (BK * 2) + c4 * 8;
            byte ^= ((row & 7) << 4);
            *(bf16x4*)((char*)lds_x + byte) = h;
        }
        // ---- stage W chunk: 512 rows x 64 k, 8192 float4 = 16/thread
        #pragma unroll
        for (int p = 0; p < 16; ++p) {
            int idx4 = tid + p * 512;
            int row  = idx4 >> 4;          // j
            int c4   = idx4 & 15;
            float4 v = *(const float4*)(wi + (size_t)row * Dd + k0 + c4 * 4);
            bf16x4 h;
            h[0] = (short)f2bf(v.x); h[1] = (short)f2bf(v.y);
            h[2] = (short)f2bf(v.z); h[3] = (short)f2bf(v.w);
            int byte = row * (BK * 2) + c4 * 8;
            byte ^= ((row & 7) << 4);
            *(bf16x4*)((char*)lds_w + byte) = h;
        }
        __syncthreads();

        // ---- MFMA phase: 2 K-slices of 32, 8 M-tiles x 4 N-tiles each
        #pragma unroll
        for (int kk = 0; kk < 2; ++kk) {
            const int colb = kk * 64 + (lane >> 4) * 16;   // byte col within 128B row
            bf16x8 bf[4];
            #pragma unroll
            for (int nt = 0; nt < 4; ++nt) {
                int row  = wid * 64 + nt * 16 + (lane & 15);
                int byte = row * (BK * 2) + (colb ^ ((row & 7) << 4));
                bf[nt] = *(const bf16x8*)((const char*)lds_w + byte);
            }
            #pragma unroll
            for (int mt = 0; mt < 8; ++mt) {
                int row  = mt * 16 + (lane & 15);
                int byte = row * (BK * 2) + (colb ^ ((row & 7) << 4));
                bf16x8 af = *(const bf16x8*)((const char*)lds_x + byte);
                #pragma unroll
                for (int nt = 0; nt < 4; ++nt)
                    acc[mt][nt] = __builtin_amdgcn_mfma_f32_16x16x32_bf16(
                        af, bf[nt], acc[mt][nt], 0, 0, 0);
            }
        }
    }

    // ---- epilogue: C row = (lane>>4)*4 + r, col = lane&15  [m89-verified layout]
    const int j0     = wid * 64 + (lane & 15);
    const int n_base = (lane >> 4) * 4;
    float* oi = out + (size_t)i * Dd;
    #pragma unroll
    for (int mt = 0; mt < 8; ++mt) {
        #pragma unroll
        for (int r = 0; r < 4; ++r) {
            int n = mt * 16 + n_base + r;
            float* orow = oi + (size_t)n * (Dd * Dd);
            #pragma unroll
            for (int nt = 0; nt < 4; ++nt)
                orow[j0 + nt * 16] = acc[mt][nt][r] + bias_v[nt];
        }
    }
}

extern "C" void kernel_launch(void* const* d_in, const int* in_sizes, int n_in,
                              void* d_out, int out_size, void* d_ws, size_t ws_size,
                              hipStream_t stream) {
    const float* x = (const float*)d_in[0];
    const float* w = (const float*)d_in[1];
    const float* b = (const float*)d_in[2];
    float* out = (float*)d_out;
    linear3d_kernel<<<dim3(Dd), dim3(512), 0, stream>>>(x, w, b, out);
}

// Round 2
// 201.755 us; speedup vs baseline: 1.2569x; 1.2569x over previous
//
#include <hip/hip_runtime.h>

// out[n,i,j] = sum_k x[n,i,k] * w[i,j,k] + b[i,j]   (N=128, D=512)
// One block per i. j-chunks of 16 rows at FULL K: W read as 32KB contiguous
// chunks (perfect streaming), X held in registers (64 VGPR/lane), acc = 4 VGPR.
// LDS = 32KB (double-buffered W chunk) -> 2 blocks/CU, 16 waves/CU.

#define Nn 128
#define Dd 512
#define CHUNK 16            // j rows per chunk
#define NCHUNK (Dd / CHUNK) // 32

typedef __attribute__((ext_vector_type(8))) short bf16x8;   // MFMA A/B fragment
typedef __attribute__((ext_vector_type(4))) short bf16x4;   // 8B LDS write
typedef __attribute__((ext_vector_type(4))) float f32x4;    // MFMA C/D fragment

__device__ __forceinline__ short f2bf(float f) {
    unsigned u = __builtin_bit_cast(unsigned, f);
    u += 0x7FFFu + ((u >> 16) & 1u);      // round-to-nearest-even
    return (short)(u >> 16);
}

__global__ __launch_bounds__(512, 4)
void linear3d_kernel(const float* __restrict__ x,
                     const float* __restrict__ w,
                     const float* __restrict__ b,
                     float* __restrict__ out) {
    const int i    = blockIdx.x;
    const int tid  = threadIdx.x;
    const int lane = tid & 63;
    const int wid  = tid >> 6;            // 8 waves; wave owns n rows [wid*16, wid*16+16)

    // 32KB: double-buffered W chunk [16][512] bf16; also reused as X staging (32 rows)
    __shared__ short lds[2 * CHUNK * Dd];

    const float* xi = x + (size_t)i * Dd;             // x[n,i,k] = xi[n*Dd*Dd + k]
    const float* wi = w + (size_t)i * Dd * Dd;        // w[i,j,k] = wi[j*Dd + k]

    // ---- issue W chunk 0 loads early (latency hidden under X staging)
    float4 wreg[4];
    #pragma unroll
    for (int p = 0; p < 4; ++p)
        wreg[p] = *(const float4*)(wi + (size_t)(tid + p * 512) * 4);

    // ---- stage X into per-wave register fragments via LDS, 4 rounds of 32 rows.
    // xf[s] = A-fragment for k-slice s: lane holds X[nb + (lane&15)][s*32 + (lane>>4)*8 ..+8]
    bf16x8 xf[16];
    #pragma unroll 4
    for (int r = 0; r < 4; ++r) {
        __syncthreads();                  // protect previous round's fragment reads
        #pragma unroll
        for (int p = 0; p < 8; ++p) {
            int idx4 = tid + p * 512;     // [0, 4096): 32 rows x 128 float4
            int row  = idx4 >> 7;
            int c4   = idx4 & 127;
            float4 v = *(const float4*)(xi + (size_t)(r * 32 + row) * (Dd * Dd) + c4 * 4);
            bf16x4 h = { f2bf(v.x), f2bf(v.y), f2bf(v.z), f2bf(v.w) };
            int byte = row * 1024 + c4 * 8;
            byte ^= (row & 7) << 4;       // T2 XOR swizzle
            *(bf16x4*)((char*)lds + byte) = h;
        }
        __syncthreads();
        if ((wid >> 1) == r) {            // the 2 waves whose rows are staged this round
            int row = (wid & 1) * 16 + (lane & 15);
            #pragma unroll
            for (int s = 0; s < 16; ++s) {
                int byte = row * 1024 + s * 64 + (lane >> 4) * 16;
                byte ^= (row & 7) << 4;
                xf[s] = *(const bf16x8*)((const char*)lds + byte);
            }
        }
    }
    __syncthreads();

    // ---- convert & write W chunk 0 into buf0
    #pragma unroll
    for (int p = 0; p < 4; ++p) {
        int idx4 = tid + p * 512;         // [0, 2048): 16 rows x 128 float4
        int row  = idx4 >> 7;
        int c4   = idx4 & 127;
        bf16x4 h = { f2bf(wreg[p].x), f2bf(wreg[p].y), f2bf(wreg[p].z), f2bf(wreg[p].w) };
        int byte = row * 1024 + c4 * 8;
        byte ^= (row & 7) << 4;
        *(bf16x4*)((char*)lds + byte) = h;
    }
    __syncthreads();

    const int nb = wid * 16;
    float* outbase = out + (size_t)i * Dd;

    for (int c = 0; c < NCHUNK; ++c) {
        // ---- issue next W chunk loads (in flight across compute; the barrier's
        // vmcnt(0) drain lands exactly where the convert needs them anyway)
        if (c + 1 < NCHUNK) {
            const float* src = wi + (size_t)(c + 1) * (CHUNK * Dd);
            #pragma unroll
            for (int p = 0; p < 4; ++p)
                wreg[p] = *(const float4*)(src + (size_t)(tid + p * 512) * 4);
        }

        // ---- compute: 16 k-slices, B-fragments from LDS, A from registers
        const char* buf = (const char*)lds + (c & 1) * (CHUNK * Dd * 2);
        f32x4 acc = {0.f, 0.f, 0.f, 0.f};
        #pragma unroll
        for (int s = 0; s < 16; ++s) {
            int row  = lane & 15;         // j within chunk
            int byte = row * 1024 + s * 64 + (lane >> 4) * 16;
            byte ^= (row & 7) << 4;
            bf16x8 wf = *(const bf16x8*)(buf + byte);
            acc = __builtin_amdgcn_mfma_f32_16x16x32_bf16(xf[s], wf, acc, 0, 0, 0);
        }

        // ---- epilogue: this chunk's output is final (full K reduced)
        float bias = b[i * Dd + c * CHUNK + (lane & 15)];
        #pragma unroll
        for (int r = 0; r < 4; ++r) {
            int n = nb + (lane >> 4) * 4 + r;     // C row = (lane>>4)*4 + r
            outbase[(size_t)n * (Dd * Dd) + c * CHUNK + (lane & 15)] = acc[r] + bias;
        }

        __syncthreads();                  // all waves done reading buf[c&1]
        if (c + 1 < NCHUNK) {
            char* dst = (char*)lds + ((c + 1) & 1) * (CHUNK * Dd * 2);
            #pragma unroll
            for (int p = 0; p < 4; ++p) {
                int idx4 = tid + p * 512;
                int row  = idx4 >> 7;
                int c4   = idx4 & 127;
                bf16x4 h = { f2bf(wreg[p].x), f2bf(wreg[p].y), f2bf(wreg[p].z), f2bf(wreg[p].w) };
                int byte = row * 1024 + c4 * 8;
                byte ^= (row & 7) << 4;
                *(bf16x4*)(dst + byte) = h;
            }
        }
        __syncthreads();                  // next chunk's buffer ready
    }
}

extern "C" void kernel_launch(void* const* d_in, const int* in_sizes, int n_in,
                              void* d_out, int out_size, void* d_ws, size_t ws_size,
                              hipStream_t stream) {
    const float* x = (const float*)d_in[0];
    const float* w = (const float*)d_in[1];
    const float* b = (const float*)d_in[2];
    float* out = (float*)d_out;
    linear3d_kernel<<<dim3(Dd), dim3(512), 0, stream>>>(x, w, b, out);
}